// Round 2
// baseline (3082.463 us; speedup 1.0000x reference)
//
#include <hip/hip_runtime.h>
#include <hip/hip_bf16.h>

// ---------- types ----------
typedef __attribute__((ext_vector_type(8))) short short8;   // 8 bf16 = 4 VGPRs (MFMA A/B frag)
typedef __attribute__((ext_vector_type(4))) short short4_t; // 4 bf16
typedef __attribute__((ext_vector_type(4))) float f32x4;    // MFMA C/D frag

__device__ __forceinline__ short f2bf(float x) {
  unsigned int u = __builtin_bit_cast(unsigned int, x);
  unsigned int r = (u + 0x7fffu + ((u >> 16) & 1u)) >> 16;
  return (short)r;
}
__device__ __forceinline__ float bf2f(unsigned short u) {
  unsigned int i = ((unsigned int)u) << 16;
  return __builtin_bit_cast(float, i);
}

#define HDIM 1024   // bytes-free name kept; H = 512 elements
#define HROW 520    // shorts per h_lds row (1040 B)

// lgkmcnt-only barrier: LDS ordering without draining vmcnt (keeps global
// prefetches in flight across the barrier — the m97-structure fix).
#define LDS_BARRIER() asm volatile("s_waitcnt lgkmcnt(0)\n\ts_barrier" ::: "memory")

// ---------- kernel W: convert Wh fp32 -> bf16 ----------
__global__ __launch_bounds__(256) void kcvt(const float* __restrict__ Wh,
                                            short* __restrict__ Whb) {
  int i = blockIdx.x * 256 + threadIdx.x;          // 65536 float4 groups
  float4 v = ((const float4*)Wh)[i];
  short4_t o;
  o[0] = f2bf(v.x); o[1] = f2bf(v.y); o[2] = f2bf(v.z); o[3] = f2bf(v.w);
  ((short4_t*)Whb)[i] = o;
}

// ---------- kernel A: xp[s][b][h] = sum_e emb[ids[b][s]][e]*Wi[h][e] + bi[h] + bh[h] (bf16) ----------
__global__ __launch_bounds__(256) void kxproj(const int* __restrict__ ids,    // [B=64][S=512]
                                              const float* __restrict__ emb,  // [V][256]
                                              const float* __restrict__ Wi,   // [512][256]
                                              const float* __restrict__ bi,   // [512]
                                              const float* __restrict__ bh,   // [512]
                                              short* __restrict__ xp) {       // [S][64][512] bf16
  const int s  = blockIdx.x;       // 0..511
  const int hb = blockIdx.y;       // 0..1  (h-block of 256)
  // one LDS arena, reused: phase 1 = emb_t + wi_t (fp32), phase 2 = stage (bf16)
  __shared__ __align__(16) char smem[42240];
  float* emb_t = (float*)smem;              // [32][68]  = 8704 B
  float* wi_t  = (float*)(smem + 8704);     // [32][260] = 33280 B (ends 41984)
  short* stage = (short*)smem;              // [64][264] = 33792 B (phase 2)
  __shared__ int ids_s[64];
  const int tid = threadIdx.x;
  const int b0 = (tid & 7) * 8;    // 8 batches per thread
  const int h0 = (tid >> 3) * 8;   // 8 h per thread (h-local 0..255)

  if (tid < 64) ids_s[tid] = ids[tid * 512 + s];
  __syncthreads();

  float acc[8][8];
  #pragma unroll
  for (int i = 0; i < 8; ++i)
    #pragma unroll
    for (int j = 0; j < 8; ++j) acc[i][j] = 0.f;

  for (int ec = 0; ec < 256; ec += 32) {
    #pragma unroll
    for (int j = 0; j < 8; ++j) {
      int idx = j * 256 + tid;
      int e = idx & 31, b = idx >> 5;
      emb_t[e * 68 + b] = emb[ids_s[b] * 256 + ec + e];
    }
    #pragma unroll
    for (int j = 0; j < 8; ++j) {
      int idx4 = j * 256 + tid;
      int e4 = (idx4 & 7) * 4, hl = idx4 >> 3;
      float4 f = *(const float4*)&Wi[(hb * 256 + hl) * 256 + ec + e4];
      wi_t[(e4 + 0) * 260 + hl] = f.x;
      wi_t[(e4 + 1) * 260 + hl] = f.y;
      wi_t[(e4 + 2) * 260 + hl] = f.z;
      wi_t[(e4 + 3) * 260 + hl] = f.w;
    }
    __syncthreads();
    for (int e = 0; e < 32; ++e) {
      const float4 eb0 = *(const float4*)&emb_t[e * 68 + b0];
      const float4 eb1 = *(const float4*)&emb_t[e * 68 + b0 + 4];
      const float4 w0  = *(const float4*)&wi_t[e * 260 + h0];
      const float4 w1  = *(const float4*)&wi_t[e * 260 + h0 + 4];
      float av[8] = {eb0.x, eb0.y, eb0.z, eb0.w, eb1.x, eb1.y, eb1.z, eb1.w};
      float wv[8] = {w0.x, w0.y, w0.z, w0.w, w1.x, w1.y, w1.z, w1.w};
      #pragma unroll
      for (int i = 0; i < 8; ++i)
        #pragma unroll
        for (int j = 0; j < 8; ++j) acc[i][j] += av[i] * wv[j];
    }
    __syncthreads();
  }
  // phase 2a: bias + cvt, write transposed tile [b][h] into stage
  float add[8];
  #pragma unroll
  for (int hj = 0; hj < 8; ++hj) { int h = hb * 256 + h0 + hj; add[hj] = bi[h] + bh[h]; }
  #pragma unroll
  for (int b2 = 0; b2 < 8; ++b2) {
    short8 pk;
    #pragma unroll
    for (int hj = 0; hj < 8; ++hj) pk[hj] = f2bf(acc[b2][hj] + add[hj]);
    *(short8*)&stage[(b0 + b2) * 264 + h0] = pk;
  }
  __syncthreads();
  // phase 2b: coalesced write-out; xp[s][b][h] with h contiguous
  {
    int n = tid >> 2, ch = tid & 3;   // n: batch 0..63, ch: 64-h chunk 0..3
    const short* src = &stage[n * 264 + ch * 64];
    short* dst = &xp[((size_t)s * 64 + n) * 512 + hb * 256 + ch * 64];
    #pragma unroll
    for (int j = 0; j < 8; ++j) *(short8*)&dst[j * 8] = *(const short8*)&src[j * 8];
  }
}

// ---------- kernel B: the recurrence. 4 WGs x 16 batches, 4 waves each. ----------
// Wave w owns output rows [128w, 128w+128): tiles t=0..5 register-resident
// (384 VGPRs), t=6,7 streamed from L2 with depth-1 ping-pong. h state (16
// batches x 512 bf16) in LDS. Barriers are lgkmcnt-only so all global
// prefetches (x for next step, streamed A) stay in flight across them.
__global__ __launch_bounds__(256, 1) void krnn(const short* __restrict__ Whb, // [512][512] bf16
                                               const short* __restrict__ xp,  // [S][64][512] bf16
                                               float* __restrict__ d_out) {
  __shared__ short h_lds[16 * HROW];   // 16,640 B
  const int tid = threadIdx.x;
  const int w   = tid >> 6;       // wave 0..3
  const int l   = tid & 63;
  const int n   = l & 15;         // MFMA col / batch-in-group
  const int q   = l >> 4;         // quad 0..3
  const int g   = blockIdx.x;     // batch group 0..3
  const int m0  = w * 128;

  for (int i = tid; i < 16 * HROW / 2; i += 256) ((int*)h_lds)[i] = 0;

  // register A-frags, tiles 0..5: A[m = n][k = q*8+j]
  short8 areg[6][16];
  #pragma unroll
  for (int t = 0; t < 6; ++t) {
    const short* base = &Whb[(m0 + t * 16 + n) * 512 + q * 8];
    #pragma unroll
    for (int kt = 0; kt < 16; ++kt) areg[t][kt] = *(const short8*)&base[kt * 32];
  }
  const short* a6 = &Whb[(m0 +  96 + n) * 512 + q * 8];
  const short* a7 = &Whb[(m0 + 112 + n) * 512 + q * 8];
  __syncthreads();

  // x for current step: row = (s*64 + g*16 + n), 8 short4 chunks (t tiles, q offset)
  const short* xrow = &xp[(size_t)(g * 16 + n) * 512 + m0];
  short4_t xv[8];
  #pragma unroll
  for (int t = 0; t < 8; ++t) xv[t] = *(const short4_t*)&xrow[t * 16 + q * 4];

  short8 c6 = *(const short8*)&a6[0];
  short8 c7 = *(const short8*)&a7[0];

  for (int s = 0; s < 512; ++s) {
    f32x4 acc[8];
    #pragma unroll
    for (int t = 0; t < 8; ++t) acc[t] = (f32x4){0.f, 0.f, 0.f, 0.f};

    #pragma unroll
    for (int kt = 0; kt < 16; ++kt) {
      short8 n6, n7;
      if (kt < 15) { n6 = *(const short8*)&a6[(kt + 1) * 32]; n7 = *(const short8*)&a7[(kt + 1) * 32]; }
      short8 bfrag = *(const short8*)&h_lds[n * HROW + kt * 32 + q * 8];
      acc[0] = __builtin_amdgcn_mfma_f32_16x16x32_bf16(areg[0][kt], bfrag, acc[0], 0, 0, 0);
      acc[1] = __builtin_amdgcn_mfma_f32_16x16x32_bf16(areg[1][kt], bfrag, acc[1], 0, 0, 0);
      acc[2] = __builtin_amdgcn_mfma_f32_16x16x32_bf16(areg[2][kt], bfrag, acc[2], 0, 0, 0);
      acc[3] = __builtin_amdgcn_mfma_f32_16x16x32_bf16(areg[3][kt], bfrag, acc[3], 0, 0, 0);
      acc[4] = __builtin_amdgcn_mfma_f32_16x16x32_bf16(areg[4][kt], bfrag, acc[4], 0, 0, 0);
      acc[5] = __builtin_amdgcn_mfma_f32_16x16x32_bf16(areg[5][kt], bfrag, acc[5], 0, 0, 0);
      acc[6] = __builtin_amdgcn_mfma_f32_16x16x32_bf16(c6,          bfrag, acc[6], 0, 0, 0);
      acc[7] = __builtin_amdgcn_mfma_f32_16x16x32_bf16(c7,          bfrag, acc[7], 0, 0, 0);
      if (kt < 15) { c6 = n6; c7 = n7; }
    }
    LDS_BARRIER();   // all waves' h reads done (lgkm only; VMEM stays in flight)

    // epilogue: z = Wh.h + x, h' = sigmoid(z); write back [n][k]
    #pragma unroll
    for (int t = 0; t < 8; ++t) {
      short4_t hh;
      #pragma unroll
      for (int i = 0; i < 4; ++i) {
        float z = acc[t][i] + bf2f((unsigned short)xv[t][i]);
        float hv = 1.f / (1.f + __expf(-z));
        hh[i] = f2bf(hv);
        if (s == 511) {
          int m = m0 + t * 16 + q * 4 + i;
          d_out[64 + (g * 16 + n) * 512 + m] = hv;
        }
      }
      *(short4_t*)&h_lds[n * HROW + m0 + t * 16 + q * 4] = hh;
    }

    // prefetch next step's x (consumed regs now free) + re-arm streamed tiles
    xrow += 64 * 512;
    if (s < 511) {
      #pragma unroll
      for (int t = 0; t < 8; ++t) xv[t] = *(const short4_t*)&xrow[t * 16 + q * 4];
    }
    c6 = *(const short8*)&a6[0];
    c7 = *(const short8*)&a7[0];

    LDS_BARRIER();   // h' visible to all waves
  }
}

// ---------- kernel C: sig[b] = sigmoid(hidden[b] . Wf + bf) ----------
__global__ __launch_bounds__(256) void kfin(const float* __restrict__ hid,  // d_out+64, [64][512]
                                            const float* __restrict__ Wf,   // [512]
                                            const float* __restrict__ bfp,  // [1]
                                            float* __restrict__ out) {
  __shared__ float red[4][64];
  int t = threadIdx.x, b = t & 63, qq = t >> 6;
  const float4* hv = (const float4*)&hid[b * 512 + qq * 128];
  const float4* wv = (const float4*)&Wf[qq * 128];
  float p = 0.f;
  #pragma unroll 8
  for (int k = 0; k < 32; ++k) {
    float4 hx = hv[k]; float4 wx = wv[k];
    p += hx.x * wx.x + hx.y * wx.y + hx.z * wx.z + hx.w * wx.w;
  }
  red[qq][b] = p;
  __syncthreads();
  if (t < 64) {
    float z = red[0][t] + red[1][t] + red[2][t] + red[3][t] + bfp[0];
    out[t] = 1.f / (1.f + __expf(-z));
  }
}

extern "C" void kernel_launch(void* const* d_in, const int* in_sizes, int n_in,
                              void* d_out, int out_size, void* d_ws, size_t ws_size,
                              hipStream_t stream) {
  const int*   ids = (const int*)d_in[0];
  const float* emb = (const float*)d_in[1];
  const float* Wh  = (const float*)d_in[2];
  const float* bh  = (const float*)d_in[3];
  const float* Wi  = (const float*)d_in[4];
  const float* bi  = (const float*)d_in[5];
  const float* Wf  = (const float*)d_in[6];
  const float* bf_ = (const float*)d_in[7];
  float* out = (float*)d_out;

  short* xp  = (short*)d_ws;                              // [512][64][512] bf16 = 32 MiB
  short* Whb = (short*)((char*)d_ws + (size_t)33554432);  // [512][512] bf16 = 512 KiB
  (void)in_sizes; (void)n_in; (void)out_size; (void)ws_size;

  kcvt  <<<256, 256, 0, stream>>>(Wh, Whb);
  kxproj<<<dim3(512, 2), 256, 0, stream>>>(ids, emb, Wi, bi, bh, xp);
  krnn  <<<4, 256, 0, stream>>>(Whb, xp, out);
  kfin  <<<1, 256, 0, stream>>>(out + 64, Wf, bf_, out);
}

// Round 4
// 1913.551 us; speedup vs baseline: 1.6109x; 1.6109x over previous
//
#include <hip/hip_runtime.h>
#include <hip/hip_bf16.h>

// ---------- types ----------
typedef __attribute__((ext_vector_type(8))) short short8;   // 8 bf16 = 4 VGPRs (MFMA A/B frag)
typedef __attribute__((ext_vector_type(4))) short short4_t; // 4 bf16
typedef __attribute__((ext_vector_type(4))) float f32x4;    // MFMA C/D frag

__device__ __forceinline__ short f2bf(float x) {
  unsigned int u = __builtin_bit_cast(unsigned int, x);
  unsigned int r = (u + 0x7fffu + ((u >> 16) & 1u)) >> 16;
  return (short)r;
}
__device__ __forceinline__ float bf2f(unsigned short u) {
  unsigned int i = ((unsigned int)u) << 16;
  return __builtin_bit_cast(float, i);
}

// packed f32x2 -> bf16x2 as an int (hardware cvt if available; safe fallback)
__device__ __forceinline__ int pkcvt(float a, float b) {
#if __has_builtin(__builtin_amdgcn_cvt_pk_bf16_f32)
  typedef __attribute__((ext_vector_type(2))) __bf16 bf16x2_t;
  bf16x2_t r = __builtin_amdgcn_cvt_pk_bf16_f32(a, b);
  return __builtin_bit_cast(int, r);
#else
  unsigned int lo = (unsigned short)f2bf(a);
  unsigned int hi = (unsigned short)f2bf(b);
  return (int)(lo | (hi << 16));
#endif
}

#define HROW 520    // shorts per LDS row (1040 B: 16B-aligned, 2-way bank alias = free)

// lgkmcnt-only barrier: LDS ordering without draining vmcnt (keeps global
// prefetches in flight across the barrier).
#define LDS_BARRIER() asm volatile("s_waitcnt lgkmcnt(0)\n\ts_barrier" ::: "memory")

// ---------- kernel W: convert Wh fp32 -> bf16 ----------
__global__ __launch_bounds__(256) void kcvt(const float* __restrict__ Wh,
                                            short* __restrict__ Whb) {
  int i = blockIdx.x * 256 + threadIdx.x;          // 65536 float4 groups
  float4 v = ((const float4*)Wh)[i];
  short4_t o;
  o[0] = f2bf(v.x); o[1] = f2bf(v.y); o[2] = f2bf(v.z); o[3] = f2bf(v.w);
  ((short4_t*)Whb)[i] = o;
}

// ---------- kernel A: xp[s][b][h] = sum_e emb[ids[b][s]][e]*Wi[h][e] + bi[h] + bh[h] (bf16) ----------
__global__ __launch_bounds__(256) void kxproj(const int* __restrict__ ids,    // [B=64][S=512]
                                              const float* __restrict__ emb,  // [V][256]
                                              const float* __restrict__ Wi,   // [512][256]
                                              const float* __restrict__ bi,   // [512]
                                              const float* __restrict__ bh,   // [512]
                                              short* __restrict__ xp) {       // [S][64][512] bf16
  const int s  = blockIdx.x;       // 0..511
  const int hb = blockIdx.y;       // 0..1  (h-block of 256)
  __shared__ __align__(16) char smem[42240];
  float* emb_t = (float*)smem;              // [32][68]  = 8704 B
  float* wi_t  = (float*)(smem + 8704);     // [32][260] = 33280 B
  short* stage = (short*)smem;              // [64][264] = 33792 B (phase 2)
  __shared__ int ids_s[64];
  const int tid = threadIdx.x;
  const int b0 = (tid & 7) * 8;
  const int h0 = (tid >> 3) * 8;

  if (tid < 64) ids_s[tid] = ids[tid * 512 + s];
  __syncthreads();

  float acc[8][8];
  #pragma unroll
  for (int i = 0; i < 8; ++i)
    #pragma unroll
    for (int j = 0; j < 8; ++j) acc[i][j] = 0.f;

  for (int ec = 0; ec < 256; ec += 32) {
    #pragma unroll
    for (int j = 0; j < 8; ++j) {
      int idx = j * 256 + tid;
      int e = idx & 31, b = idx >> 5;
      emb_t[e * 68 + b] = emb[ids_s[b] * 256 + ec + e];
    }
    #pragma unroll
    for (int j = 0; j < 8; ++j) {
      int idx4 = j * 256 + tid;
      int e4 = (idx4 & 7) * 4, hl = idx4 >> 3;
      float4 f = *(const float4*)&Wi[(hb * 256 + hl) * 256 + ec + e4];
      wi_t[(e4 + 0) * 260 + hl] = f.x;
      wi_t[(e4 + 1) * 260 + hl] = f.y;
      wi_t[(e4 + 2) * 260 + hl] = f.z;
      wi_t[(e4 + 3) * 260 + hl] = f.w;
    }
    __syncthreads();
    for (int e = 0; e < 32; ++e) {
      const float4 eb0 = *(const float4*)&emb_t[e * 68 + b0];
      const float4 eb1 = *(const float4*)&emb_t[e * 68 + b0 + 4];
      const float4 w0  = *(const float4*)&wi_t[e * 260 + h0];
      const float4 w1  = *(const float4*)&wi_t[e * 260 + h0 + 4];
      float av[8] = {eb0.x, eb0.y, eb0.z, eb0.w, eb1.x, eb1.y, eb1.z, eb1.w};
      float wv[8] = {w0.x, w0.y, w0.z, w0.w, w1.x, w1.y, w1.z, w1.w};
      #pragma unroll
      for (int i = 0; i < 8; ++i)
        #pragma unroll
        for (int j = 0; j < 8; ++j) acc[i][j] += av[i] * wv[j];
    }
    __syncthreads();
  }
  float add[8];
  #pragma unroll
  for (int hj = 0; hj < 8; ++hj) { int h = hb * 256 + h0 + hj; add[hj] = bi[h] + bh[h]; }
  #pragma unroll
  for (int b2 = 0; b2 < 8; ++b2) {
    short8 pk;
    #pragma unroll
    for (int hj = 0; hj < 8; ++hj) pk[hj] = f2bf(acc[b2][hj] + add[hj]);
    *(short8*)&stage[(b0 + b2) * 264 + h0] = pk;
  }
  __syncthreads();
  {
    int n = tid >> 2, ch = tid & 3;
    const short* src = &stage[n * 264 + ch * 64];
    short* dst = &xp[((size_t)s * 64 + n) * 512 + hb * 256 + ch * 64];
    #pragma unroll
    for (int j = 0; j < 8; ++j) *(short8*)&dst[j * 8] = *(const short8*)&src[j * 8];
  }
}

// ---------- kernel B: the recurrence. 4 WGs x 16 batches, 4 waves each. ----------
// Wave w owns rows [128w, 128w+128): tiles 0..5 register-resident (384 regs,
// 512-reg budget at 1 wave/SIMD), tiles 6,7 LDS-resident (preloaded once;
// ds_read_b128 per kt — throughput pipe, no L2 latency in the loop).
// h state (16 batches x 512 bf16) in LDS. Barriers are lgkmcnt-only.
__global__ __launch_bounds__(256, 1) void krnn(const short* __restrict__ Whb, // [512][512] bf16
                                               const short* __restrict__ xp,  // [S][64][512] bf16
                                               float* __restrict__ d_out) {
  __shared__ short h_lds[16 * HROW];        // 16,640 B
  __shared__ short a_lds[8][16 * HROW];     // 8 tiles x 16 rows: 133,120 B (total 149,760)
  const int tid = threadIdx.x;
  const int w   = tid >> 6;       // wave 0..3
  const int l   = tid & 63;
  const int n   = l & 15;         // MFMA col / batch-in-group / A-row-in-tile
  const int q   = l >> 4;         // quad 0..3
  const int g   = blockIdx.x;     // batch group 0..3
  const int m0  = w * 128;

  for (int i = tid; i < 16 * HROW / 2; i += 256) ((int*)h_lds)[i] = 0;

  // preload LDS-resident A tiles: rows m0+96 .. m0+127 (this wave's tiles 6,7)
  for (int j = 0; j < 32; ++j) {
    int tile = w * 2 + (j >> 4), m16 = j & 15;
    *(short8*)&a_lds[tile][m16 * HROW + l * 8] =
        *(const short8*)&Whb[(m0 + 96 + j) * 512 + l * 8];
  }

  // register A-frags, tiles 0..5: A[m = n][k = q*8+j]
  short8 areg[6][16];
  #pragma unroll
  for (int t = 0; t < 6; ++t) {
    const short* base = &Whb[(m0 + t * 16 + n) * 512 + q * 8];
    #pragma unroll
    for (int kt = 0; kt < 16; ++kt) areg[t][kt] = *(const short8*)&base[kt * 32];
  }
  __syncthreads();

  const short* a6l = &a_lds[w * 2 + 0][n * HROW + q * 8];
  const short* a7l = &a_lds[w * 2 + 1][n * HROW + q * 8];

  // x for current step: 8 short4 chunks (t tiles, q offset)
  const short* xrow = &xp[(size_t)(g * 16 + n) * 512 + m0];
  short4_t xv[8];
  #pragma unroll
  for (int t = 0; t < 8; ++t) xv[t] = *(const short4_t*)&xrow[t * 16 + q * 4];

  for (int s = 0; s < 512; ++s) {
    f32x4 acc[8];
    #pragma unroll
    for (int t = 0; t < 8; ++t) acc[t] = (f32x4){0.f, 0.f, 0.f, 0.f};

    #pragma unroll
    for (int kt = 0; kt < 16; ++kt) {
      short8 bfrag = *(const short8*)&h_lds[n * HROW + kt * 32 + q * 8];
      short8 a6 = *(const short8*)&a6l[kt * 32];
      short8 a7 = *(const short8*)&a7l[kt * 32];
      acc[0] = __builtin_amdgcn_mfma_f32_16x16x32_bf16(areg[0][kt], bfrag, acc[0], 0, 0, 0);
      acc[1] = __builtin_amdgcn_mfma_f32_16x16x32_bf16(areg[1][kt], bfrag, acc[1], 0, 0, 0);
      acc[2] = __builtin_amdgcn_mfma_f32_16x16x32_bf16(areg[2][kt], bfrag, acc[2], 0, 0, 0);
      acc[3] = __builtin_amdgcn_mfma_f32_16x16x32_bf16(areg[3][kt], bfrag, acc[3], 0, 0, 0);
      acc[4] = __builtin_amdgcn_mfma_f32_16x16x32_bf16(areg[4][kt], bfrag, acc[4], 0, 0, 0);
      acc[5] = __builtin_amdgcn_mfma_f32_16x16x32_bf16(areg[5][kt], bfrag, acc[5], 0, 0, 0);
      acc[6] = __builtin_amdgcn_mfma_f32_16x16x32_bf16(a6,          bfrag, acc[6], 0, 0, 0);
      acc[7] = __builtin_amdgcn_mfma_f32_16x16x32_bf16(a7,          bfrag, acc[7], 0, 0, 0);
    }
    LDS_BARRIER();   // all waves' h reads done (lgkm only; VMEM stays in flight)

    // epilogue: z = Wh.h + x, h' = sigmoid(z); write back [n][k]
    #pragma unroll
    for (int t = 0; t < 8; ++t) {
      float hv4[4];
      #pragma unroll
      for (int i = 0; i < 4; ++i) {
        float z = acc[t][i] + bf2f((unsigned short)xv[t][i]);
        float e = __expf(-z);
        hv4[i] = __builtin_amdgcn_rcpf(1.f + e);
      }
      int2 hpk;
      hpk.x = pkcvt(hv4[0], hv4[1]);
      hpk.y = pkcvt(hv4[2], hv4[3]);
      if (s == 511) {
        #pragma unroll
        for (int i = 0; i < 4; ++i) {
          int m = m0 + t * 16 + q * 4 + i;
          d_out[64 + (g * 16 + n) * 512 + m] = hv4[i];
        }
      }
      *(short4_t*)&h_lds[n * HROW + m0 + t * 16 + q * 4] = __builtin_bit_cast(short4_t, hpk);
    }

    // prefetch next step's x (consumed regs now free)
    xrow += 64 * 512;
    if (s < 511) {
      #pragma unroll
      for (int t = 0; t < 8; ++t) xv[t] = *(const short4_t*)&xrow[t * 16 + q * 4];
    }

    LDS_BARRIER();   // h' visible to all waves
  }
}

// ---------- kernel C: sig[b] = sigmoid(hidden[b] . Wf + bf) ----------
__global__ __launch_bounds__(256) void kfin(const float* __restrict__ hid,  // d_out+64, [64][512]
                                            const float* __restrict__ Wf,   // [512]
                                            const float* __restrict__ bfp,  // [1]
                                            float* __restrict__ out) {
  __shared__ float red[4][64];
  int t = threadIdx.x, b = t & 63, qq = t >> 6;
  const float4* hv = (const float4*)&hid[b * 512 + qq * 128];
  const float4* wv = (const float4*)&Wf[qq * 128];
  float p = 0.f;
  #pragma unroll 8
  for (int k = 0; k < 32; ++k) {
    float4 hx = hv[k]; float4 wx = wv[k];
    p += hx.x * wx.x + hx.y * wx.y + hx.z * wx.z + hx.w * wx.w;
  }
  red[qq][b] = p;
  __syncthreads();
  if (t < 64) {
    float z = red[0][t] + red[1][t] + red[2][t] + red[3][t] + bfp[0];
    out[t] = 1.f / (1.f + __expf(-z));
  }
}

extern "C" void kernel_launch(void* const* d_in, const int* in_sizes, int n_in,
                              void* d_out, int out_size, void* d_ws, size_t ws_size,
                              hipStream_t stream) {
  const int*   ids = (const int*)d_in[0];
  const float* emb = (const float*)d_in[1];
  const float* Wh  = (const float*)d_in[2];
  const float* bh  = (const float*)d_in[3];
  const float* Wi  = (const float*)d_in[4];
  const float* bi  = (const float*)d_in[5];
  const float* Wf  = (const float*)d_in[6];
  const float* bf_ = (const float*)d_in[7];
  float* out = (float*)d_out;

  short* xp  = (short*)d_ws;                              // [512][64][512] bf16 = 32 MiB
  short* Whb = (short*)((char*)d_ws + (size_t)33554432);  // [512][512] bf16 = 512 KiB
  (void)in_sizes; (void)n_in; (void)out_size; (void)ws_size;

  kcvt  <<<256, 256, 0, stream>>>(Wh, Whb);
  kxproj<<<dim3(512, 2), 256, 0, stream>>>(ids, emb, Wi, bi, bh, xp);
  krnn  <<<4, 256, 0, stream>>>(Whb, xp, out);
  kfin  <<<1, 256, 0, stream>>>(out + 64, Wf, bf_, out);
}

// Round 5
// 1168.187 us; speedup vs baseline: 2.6387x; 1.6381x over previous
//
#include <hip/hip_runtime.h>
#include <hip/hip_bf16.h>

// ---------- types ----------
typedef __attribute__((ext_vector_type(8))) short short8;   // 8 bf16 = 4 VGPRs (MFMA A/B frag)
typedef __attribute__((ext_vector_type(4))) short short4_t; // 4 bf16
typedef __attribute__((ext_vector_type(4))) float f32x4;    // MFMA C/D frag

__device__ __forceinline__ short f2bf(float x) {
  unsigned int u = __builtin_bit_cast(unsigned int, x);
  unsigned int r = (u + 0x7fffu + ((u >> 16) & 1u)) >> 16;
  return (short)r;
}
__device__ __forceinline__ float bf2f(unsigned short u) {
  unsigned int i = ((unsigned int)u) << 16;
  return __builtin_bit_cast(float, i);
}

// packed f32x2 -> bf16x2 as an int (hardware cvt if available; safe fallback)
__device__ __forceinline__ int pkcvt(float a, float b) {
#if __has_builtin(__builtin_amdgcn_cvt_pk_bf16_f32)
  typedef __attribute__((ext_vector_type(2))) __bf16 bf16x2_t;
  bf16x2_t r = __builtin_amdgcn_cvt_pk_bf16_f32(a, b);
  return __builtin_bit_cast(int, r);
#else
  unsigned int lo = (unsigned short)f2bf(a);
  unsigned int hi = (unsigned short)f2bf(b);
  return (int)(lo | (hi << 16));
#endif
}

#define HROW 520    // shorts per LDS row (1040 B: 16B-aligned, 2-way bank alias = free)

// lgkmcnt-only barrier: LDS ordering without draining vmcnt (keeps global
// prefetches in flight across the barrier).
#define LDS_BARRIER() asm volatile("s_waitcnt lgkmcnt(0)\n\ts_barrier" ::: "memory")

// ---------- kernel W: convert Wh fp32 -> bf16 ----------
__global__ __launch_bounds__(256) void kcvt(const float* __restrict__ Wh,
                                            short* __restrict__ Whb) {
  int i = blockIdx.x * 256 + threadIdx.x;          // 65536 float4 groups
  float4 v = ((const float4*)Wh)[i];
  short4_t o;
  o[0] = f2bf(v.x); o[1] = f2bf(v.y); o[2] = f2bf(v.z); o[3] = f2bf(v.w);
  ((short4_t*)Whb)[i] = o;
}

// ---------- kernel A: xp[s][b][h] = sum_e emb[ids[b][s]][e]*Wi[h][e] + bi[h] + bh[h] (bf16) ----------
__global__ __launch_bounds__(256) void kxproj(const int* __restrict__ ids,    // [B=64][S=512]
                                              const float* __restrict__ emb,  // [V][256]
                                              const float* __restrict__ Wi,   // [512][256]
                                              const float* __restrict__ bi,   // [512]
                                              const float* __restrict__ bh,   // [512]
                                              short* __restrict__ xp) {       // [S][64][512] bf16
  const int s  = blockIdx.x;       // 0..511
  const int hb = blockIdx.y;       // 0..1  (h-block of 256)
  __shared__ __align__(16) char smem[42240];
  float* emb_t = (float*)smem;              // [32][68]  = 8704 B
  float* wi_t  = (float*)(smem + 8704);     // [32][260] = 33280 B
  short* stage = (short*)smem;              // [64][264] = 33792 B (phase 2)
  __shared__ int ids_s[64];
  const int tid = threadIdx.x;
  const int b0 = (tid & 7) * 8;
  const int h0 = (tid >> 3) * 8;

  if (tid < 64) ids_s[tid] = ids[tid * 512 + s];
  __syncthreads();

  float acc[8][8];
  #pragma unroll
  for (int i = 0; i < 8; ++i)
    #pragma unroll
    for (int j = 0; j < 8; ++j) acc[i][j] = 0.f;

  for (int ec = 0; ec < 256; ec += 32) {
    #pragma unroll
    for (int j = 0; j < 8; ++j) {
      int idx = j * 256 + tid;
      int e = idx & 31, b = idx >> 5;
      emb_t[e * 68 + b] = emb[ids_s[b] * 256 + ec + e];
    }
    #pragma unroll
    for (int j = 0; j < 8; ++j) {
      int idx4 = j * 256 + tid;
      int e4 = (idx4 & 7) * 4, hl = idx4 >> 3;
      float4 f = *(const float4*)&Wi[(hb * 256 + hl) * 256 + ec + e4];
      wi_t[(e4 + 0) * 260 + hl] = f.x;
      wi_t[(e4 + 1) * 260 + hl] = f.y;
      wi_t[(e4 + 2) * 260 + hl] = f.z;
      wi_t[(e4 + 3) * 260 + hl] = f.w;
    }
    __syncthreads();
    for (int e = 0; e < 32; ++e) {
      const float4 eb0 = *(const float4*)&emb_t[e * 68 + b0];
      const float4 eb1 = *(const float4*)&emb_t[e * 68 + b0 + 4];
      const float4 w0  = *(const float4*)&wi_t[e * 260 + h0];
      const float4 w1  = *(const float4*)&wi_t[e * 260 + h0 + 4];
      float av[8] = {eb0.x, eb0.y, eb0.z, eb0.w, eb1.x, eb1.y, eb1.z, eb1.w};
      float wv[8] = {w0.x, w0.y, w0.z, w0.w, w1.x, w1.y, w1.z, w1.w};
      #pragma unroll
      for (int i = 0; i < 8; ++i)
        #pragma unroll
        for (int j = 0; j < 8; ++j) acc[i][j] += av[i] * wv[j];
    }
    __syncthreads();
  }
  float add[8];
  #pragma unroll
  for (int hj = 0; hj < 8; ++hj) { int h = hb * 256 + h0 + hj; add[hj] = bi[h] + bh[h]; }
  #pragma unroll
  for (int b2 = 0; b2 < 8; ++b2) {
    short8 pk;
    #pragma unroll
    for (int hj = 0; hj < 8; ++hj) pk[hj] = f2bf(acc[b2][hj] + add[hj]);
    *(short8*)&stage[(b0 + b2) * 264 + h0] = pk;
  }
  __syncthreads();
  {
    int n = tid >> 2, ch = tid & 3;
    const short* src = &stage[n * 264 + ch * 64];
    short* dst = &xp[((size_t)s * 64 + n) * 512 + hb * 256 + ch * 64];
    #pragma unroll
    for (int j = 0; j < 8; ++j) *(short8*)&dst[j * 8] = *(const short8*)&src[j * 8];
  }
}

// ---------- kernel B: the recurrence. 4 WGs x 16 batches, 8 waves (2/SIMD). ----------
// Wave w owns rows [64w, 64w+64): tiles 0..2 register-resident (192 VGPRs —
// fits the 256-reg cap at 2 waves/SIMD, no AGPR copy churn), tile 3
// LDS-resident (preloaded once). 2 waves/SIMD co-schedule: one wave's
// ds_read/MFMA/epilogue stalls are filled by the other. h state (16 batches
// x 512 bf16) in LDS. Barriers are lgkmcnt-only (VMEM prefetch stays live).
__global__ __launch_bounds__(512, 2) void krnn(const short* __restrict__ Whb, // [512][512] bf16
                                               const short* __restrict__ xp,  // [S][64][512] bf16
                                               float* __restrict__ d_out) {
  __shared__ short h_lds[16 * HROW];        // 16,640 B
  __shared__ short a_lds[8][16 * HROW];     // 8 waves x 16 rows: 133,120 B (total 149,760)
  const int tid = threadIdx.x;
  const int w   = tid >> 6;       // wave 0..7
  const int l   = tid & 63;
  const int n   = l & 15;         // MFMA col / batch-in-group / A-row-in-tile
  const int q   = l >> 4;         // quad 0..3
  const int g   = blockIdx.x;     // batch group 0..3
  const int m0  = w * 64;

  for (int i = tid; i < 16 * HROW / 2; i += 512) ((int*)h_lds)[i] = 0;

  // preload this wave's LDS-resident A tile: rows m0+48 .. m0+63
  for (int j = 0; j < 16; ++j)
    *(short8*)&a_lds[w][j * HROW + l * 8] =
        *(const short8*)&Whb[(m0 + 48 + j) * 512 + l * 8];

  // register A-frags, tiles 0..2: A[m = n][k = q*8+j]
  short8 areg[3][16];
  #pragma unroll
  for (int t = 0; t < 3; ++t) {
    const short* base = &Whb[(m0 + t * 16 + n) * 512 + q * 8];
    #pragma unroll
    for (int kt = 0; kt < 16; ++kt) areg[t][kt] = *(const short8*)&base[kt * 32];
  }
  __syncthreads();

  const short* a3l = &a_lds[w][n * HROW + q * 8];

  // x for current step: 4 short4 chunks (t tiles, q offset)
  const short* xrow = &xp[(size_t)(g * 16 + n) * 512 + m0];
  short4_t xv[4];
  #pragma unroll
  for (int t = 0; t < 4; ++t) xv[t] = *(const short4_t*)&xrow[t * 16 + q * 4];

  for (int s = 0; s < 512; ++s) {
    f32x4 acc[4];
    #pragma unroll
    for (int t = 0; t < 4; ++t) acc[t] = (f32x4){0.f, 0.f, 0.f, 0.f};

    #pragma unroll
    for (int kt = 0; kt < 16; ++kt) {
      short8 bfrag = *(const short8*)&h_lds[n * HROW + kt * 32 + q * 8];
      short8 a3 = *(const short8*)&a3l[kt * 32];
      acc[0] = __builtin_amdgcn_mfma_f32_16x16x32_bf16(areg[0][kt], bfrag, acc[0], 0, 0, 0);
      acc[1] = __builtin_amdgcn_mfma_f32_16x16x32_bf16(areg[1][kt], bfrag, acc[1], 0, 0, 0);
      acc[2] = __builtin_amdgcn_mfma_f32_16x16x32_bf16(areg[2][kt], bfrag, acc[2], 0, 0, 0);
      acc[3] = __builtin_amdgcn_mfma_f32_16x16x32_bf16(a3,          bfrag, acc[3], 0, 0, 0);
    }
    LDS_BARRIER();   // all waves' h reads done (lgkm only; VMEM stays in flight)

    // epilogue: z = Wh.h + x, h' = sigmoid(z); write back [n][k]
    #pragma unroll
    for (int t = 0; t < 4; ++t) {
      float hv4[4];
      #pragma unroll
      for (int i = 0; i < 4; ++i) {
        float z = acc[t][i] + bf2f((unsigned short)xv[t][i]);
        float e = __expf(-z);
        hv4[i] = __builtin_amdgcn_rcpf(1.f + e);
      }
      int2 hpk;
      hpk.x = pkcvt(hv4[0], hv4[1]);
      hpk.y = pkcvt(hv4[2], hv4[3]);
      if (s == 511) {
        #pragma unroll
        for (int i = 0; i < 4; ++i) {
          int m = m0 + t * 16 + q * 4 + i;
          d_out[64 + (g * 16 + n) * 512 + m] = hv4[i];
        }
      }
      *(short4_t*)&h_lds[n * HROW + m0 + t * 16 + q * 4] = __builtin_bit_cast(short4_t, hpk);
    }

    // prefetch next step's x (consumed regs now free)
    xrow += 64 * 512;
    if (s < 511) {
      #pragma unroll
      for (int t = 0; t < 4; ++t) xv[t] = *(const short4_t*)&xrow[t * 16 + q * 4];
    }

    LDS_BARRIER();   // h' visible to all waves
  }
}

// ---------- kernel C: sig[b] = sigmoid(hidden[b] . Wf + bf) ----------
__global__ __launch_bounds__(256) void kfin(const float* __restrict__ hid,  // d_out+64, [64][512]
                                            const float* __restrict__ Wf,   // [512]
                                            const float* __restrict__ bfp,  // [1]
                                            float* __restrict__ out) {
  __shared__ float red[4][64];
  int t = threadIdx.x, b = t & 63, qq = t >> 6;
  const float4* hv = (const float4*)&hid[b * 512 + qq * 128];
  const float4* wv = (const float4*)&Wf[qq * 128];
  float p = 0.f;
  #pragma unroll 8
  for (int k = 0; k < 32; ++k) {
    float4 hx = hv[k]; float4 wx = wv[k];
    p += hx.x * wx.x + hx.y * wx.y + hx.z * wx.z + hx.w * wx.w;
  }
  red[qq][b] = p;
  __syncthreads();
  if (t < 64) {
    float z = red[0][t] + red[1][t] + red[2][t] + red[3][t] + bfp[0];
    out[t] = 1.f / (1.f + __expf(-z));
  }
}

extern "C" void kernel_launch(void* const* d_in, const int* in_sizes, int n_in,
                              void* d_out, int out_size, void* d_ws, size_t ws_size,
                              hipStream_t stream) {
  const int*   ids = (const int*)d_in[0];
  const float* emb = (const float*)d_in[1];
  const float* Wh  = (const float*)d_in[2];
  const float* bh  = (const float*)d_in[3];
  const float* Wi  = (const float*)d_in[4];
  const float* bi  = (const float*)d_in[5];
  const float* Wf  = (const float*)d_in[6];
  const float* bf_ = (const float*)d_in[7];
  float* out = (float*)d_out;

  short* xp  = (short*)d_ws;                              // [512][64][512] bf16 = 32 MiB
  short* Whb = (short*)((char*)d_ws + (size_t)33554432);  // [512][512] bf16 = 512 KiB
  (void)in_sizes; (void)n_in; (void)out_size; (void)ws_size;

  kcvt  <<<256, 256, 0, stream>>>(Wh, Whb);
  kxproj<<<dim3(512, 2), 256, 0, stream>>>(ids, emb, Wi, bi, bh, xp);
  krnn  <<<4, 512, 0, stream>>>(Whb, xp, out);
  kfin  <<<1, 256, 0, stream>>>(out + 64, Wf, bf_, out);
}